// Round 1
// 425.101 us; speedup vs baseline: 1.0498x; 1.0498x over previous
//
#include <hip/hip_runtime.h>
#include <hip/hip_bf16.h>

#define N_   32
#define C_   2048
#define ST_  16
#define H_   64      // ST*ALPHA
#define K_   3
#define CB_  512
#define LT_  400
#define LTP_ 402     // padded t rows (1 zero row each side)
#define BK   32      // K-step (bf16 elements) -> 64B LDS rows
#define TSTR 126     // M-tile stride: compute 128 rows, write 126 (2-row tap halo)

using bf16x8 = __attribute__((ext_vector_type(8))) __bf16;
using f32x4  = __attribute__((ext_vector_type(4))) float;
typedef unsigned short ushort_t;

__device__ __forceinline__ unsigned short f2bf(float f) {
    unsigned int u = __float_as_uint(f);
    u = (u + 0x7fffu + ((u >> 16) & 1u)) >> 16;
    return (unsigned short)u;
}
__device__ __forceinline__ float bf2f(unsigned short h) {
    return __uint_as_float(((unsigned int)h) << 16);
}
// async global->LDS DMA, 16B/lane. Dest = wave-uniform base + lane*16 (linear).
__device__ __forceinline__ void gload16(const ushort_t* g, ushort_t* l) {
    __builtin_amdgcn_global_load_lds(
        (const __attribute__((address_space(1))) unsigned int*)g,
        (__attribute__((address_space(3))) unsigned int*)l, 16, 0, 0);
}

// ---------------- P0: global branch -> per-(n,c) softmax kernel [NC,4] fp32
__global__ __launch_bounds__(256) void k_global(
    const float* __restrict__ st, const float* __restrict__ g_w1,
    const float* __restrict__ gam, const float* __restrict__ bet,
    const float* __restrict__ mean, const float* __restrict__ var,
    const float* __restrict__ g_w2, float* __restrict__ kern) {
    __shared__ float w1[H_][ST_];
    __shared__ float sc[H_], bi[H_];
    __shared__ float w2[K_][H_];
    int tid = threadIdx.x;
    for (int i = tid; i < H_ * ST_; i += 256) w1[i / ST_][i % ST_] = g_w1[i];
    if (tid < H_) {
        float s = gam[tid] * rsqrtf(var[tid] + 1e-5f);
        sc[tid] = s;
        bi[tid] = bet[tid] - mean[tid] * s;
    }
    for (int i = tid; i < K_ * H_; i += 256) w2[i / H_][i % H_] = g_w2[i];
    __syncthreads();
    int row = blockIdx.x * 256 + tid;  // n*C + c
    const float* p = st + (size_t)row * ST_;
    float s[ST_];
#pragma unroll
    for (int i = 0; i < ST_; ++i) s[i] = p[i];
    float lg0 = 0.f, lg1 = 0.f, lg2 = 0.f;
    for (int j = 0; j < H_; ++j) {
        float h = 0.f;
#pragma unroll
        for (int i = 0; i < ST_; ++i) h = fmaf(w1[j][i], s[i], h);
        h = fmaxf(fmaf(h, sc[j], bi[j]), 0.f);
        lg0 = fmaf(w2[0][j], h, lg0);
        lg1 = fmaf(w2[1][j], h, lg1);
        lg2 = fmaf(w2[2][j], h, lg2);
    }
    float m = fmaxf(lg0, fmaxf(lg1, lg2));
    float e0 = __expf(lg0 - m), e1 = __expf(lg1 - m), e2 = __expf(lg2 - m);
    float inv = 1.f / (e0 + e1 + e2);
    float4 o = make_float4(e0 * inv, e1 * inv, e2 * inv, 0.f);
    *(float4*)(kern + (size_t)row * 4) = o;
}

// ---------------- P1: transpose lt [n][c][t] fp32 -> ltT [n][t+1][c] bf16
// write phase vectorized: each thread stores a bf16 pair (uint)
__global__ __launch_bounds__(256) void k_transpose(
    const float* __restrict__ lt, ushort_t* __restrict__ ltT) {
    __shared__ float tile[32][33];
    int tt0 = blockIdx.x * 32;
    int cc  = blockIdx.y * 32;
    int n   = blockIdx.z;
    const float* src = lt + ((size_t)n * C_ + cc) * LT_;
    int tx = threadIdx.x & 31, ty = threadIdx.x >> 5;  // ty 0..7
#pragma unroll
    for (int i = 0; i < 4; ++i) {
        int c = ty + i * 8;
        int t = tt0 + tx;
        tile[c][tx] = (t < LT_) ? src[(size_t)c * LT_ + t] : 0.f;
    }
    __syncthreads();
    int cx  = (threadIdx.x & 15) * 2;   // c pair
    int tyw = threadIdx.x >> 4;         // 0..15
    unsigned int* dst = (unsigned int*)(ltT + (size_t)n * LTP_ * C_ + cc + cx);
#pragma unroll
    for (int i = 0; i < 2; ++i) {
        int tl = tyw + i * 16;
        int t = tt0 + tl;
        if (t < LT_) {
            unsigned int v = (unsigned int)f2bf(tile[cx][tl]) |
                             ((unsigned int)f2bf(tile[cx + 1][tl]) << 16);
            dst[(size_t)(t + 1) * (C_ / 2)] = v;
        }
    }
}

// zero the two pad rows of ltT
__global__ __launch_bounds__(256) void k_zero(ushort_t* __restrict__ ltT) {
    int i = blockIdx.x * 256 + threadIdx.x;  // over N*C
    int n = i >> 11, c = i & (C_ - 1);
    size_t base = (size_t)n * LTP_ * C_;
    ltT[base + c] = 0;
    ltT[base + (size_t)(LTP_ - 1) * C_ + c] = 0;
}

// ---------------- P2: repack l_w1 [cb][c][k] -> w1b[k][cb][c] bf16
__global__ __launch_bounds__(256) void k_w1(
    const float* __restrict__ l_w1, ushort_t* __restrict__ w1b) {
    int i = blockIdx.x * 256 + threadIdx.x;  // over CB*C
    float a = l_w1[(size_t)i * 3 + 0];
    float b = l_w1[(size_t)i * 3 + 1];
    float c = l_w1[(size_t)i * 3 + 2];
    w1b[0 * (size_t)CB_ * C_ + i] = f2bf(a);
    w1b[1 * (size_t)CB_ * C_ + i] = f2bf(b);
    w1b[2 * (size_t)CB_ * C_ + i] = f2bf(c);
}

// ---------------- P3: convert l_w2 [c][cb] -> bf16
__global__ __launch_bounds__(256) void k_w2(
    const float* __restrict__ l_w2, ushort_t* __restrict__ w2b) {
    int i = blockIdx.x * 256 + threadIdx.x;  // over C*CB
    w2b[i] = f2bf(l_w2[i]);
}

// ---------------- G1: X[n][t][cb] = ReLU(BN(sum_k W1k @ lt_shift_k)), bf16 out
// 128x128 tile (M stride 126), 2x2 waves, double-buffered global_load_lds staging,
// XOR-swizzled LDS (linear DMA dest + pre-swizzled global source + swizzled reads).
// LDS rows are 64B (BK bf16); swizzle: 16B chunk q stored at q ^ ((row>>1)&3).
__global__ __launch_bounds__(256, 2) void k_gemm1(
    const ushort_t* __restrict__ ltT, const ushort_t* __restrict__ w1b,
    const float* __restrict__ bn_g, const float* __restrict__ bn_b,
    const float* __restrict__ bn_m, const float* __restrict__ bn_v,
    ushort_t* __restrict__ Xws) {
    __shared__ __align__(16) ushort_t Asm[2 * 128 * BK];   // 16 KB (2 buf x 128 rows)
    __shared__ __align__(16) ushort_t Bsm[2 * 384 * BK];   // 48 KB (2 buf x 3 taps x 128)
    const int tid = threadIdx.x;
    const int n   = blockIdx.z;
    const int tm  = blockIdx.x * TSTR;   // padded-coords base row of A tile
    const int cb0 = blockIdx.y * 128;
    const int lane = tid & 63, lrow = lane & 15, quad = lane >> 4;
    const int wv = tid >> 6, wvM = wv & 1, wvN = wv >> 1;

    // --- staging: per-lane inverse-swizzled global sources, linear LDS dest.
    // unit = 16 rows x 64B = 1024B = one wave gload16. lane->(row srow, chunk lane&3);
    // source chunk = (lane&3) ^ s(row), s(row)=(row>>1)&3 = (lane>>3)&3 (unit-invariant).
    const int srow = lane >> 2;
    const int csrc = (((lane & 3) ^ ((lane >> 3) & 3)) << 3);  // ushort offset
    const ushort_t* gA[2];
#pragma unroll
    for (int i = 0; i < 2; ++i) {
        int r = (2 * wv + i) * 16 + srow;                 // LDS row 0..127
        int gr = tm + r; gr = gr < LTP_ - 1 ? gr : LTP_ - 1;  // clamp to pad row (zeros)
        gA[i] = ltT + ((size_t)n * LTP_ + gr) * C_ + csrc;
    }
    const ushort_t* gB[6];
#pragma unroll
    for (int j = 0; j < 6; ++j) {
        int r = (6 * wv + j) * 16 + srow;                 // LDS row 0..383 = tap*128+cbl
        gB[j] = w1b + ((size_t)((r >> 7) * CB_ + cb0 + (r & 127))) * C_ + csrc;
    }
    // --- compute-phase swizzled LDS offsets (ushort units); base rows are mult of 16
    const int sB = lrow * BK + ((quad ^ ((lrow >> 1) & 3)) << 3);
    int sA[3];
#pragma unroll
    for (int k = 0; k < 3; ++k)
        sA[k] = (lrow + k) * BK + ((quad ^ (((lrow + k) >> 1) & 3)) << 3);

    f32x4 acc[4][4];
#pragma unroll
    for (int i = 0; i < 4; ++i)
#pragma unroll
        for (int j = 0; j < 4; ++j) acc[i][j] = (f32x4){0.f, 0.f, 0.f, 0.f};

#define STAGE1(buf)                                                         \
    {                                                                       \
        ushort_t* ad = Asm + (buf) * (128 * BK) + (2 * wv) * (16 * BK);     \
        gload16(gA[0], ad);                                                 \
        gload16(gA[1], ad + 16 * BK);                                       \
        gA[0] += BK; gA[1] += BK;                                           \
        ushort_t* bd = Bsm + (buf) * (384 * BK) + (6 * wv) * (16 * BK);     \
        _Pragma("unroll")                                                   \
        for (int j = 0; j < 6; ++j) {                                       \
            gload16(gB[j], bd + j * (16 * BK));                             \
            gB[j] += BK;                                                    \
        }                                                                   \
    }

    STAGE1(0);
    for (int s = 0; s < C_ / BK; ++s) {
        __syncthreads();                 // implicit vmcnt(0): buf[cur] DMA complete
        const int cur = s & 1;
        if (s + 1 < C_ / BK) STAGE1(cur ^ 1);   // prefetch flies under the MFMAs
        const ushort_t* Ab = Asm + cur * (128 * BK) + wvM * (64 * BK);
        const ushort_t* Bb = Bsm + cur * (384 * BK) + wvN * (64 * BK) + sB;
        bf16x8 bfr[3][4];
#pragma unroll
        for (int k = 0; k < 3; ++k)
#pragma unroll
            for (int nf = 0; nf < 4; ++nf)
                bfr[k][nf] = *(const bf16x8*)(Bb + k * (128 * BK) + nf * (16 * BK));
#pragma unroll
        for (int mf = 0; mf < 4; ++mf) {
            // NOTE: tap reads for local rows 126/127 run 2 rows past the A buffer
            // (into adjacent LDS) — those accumulators only feed local>=126,
            // which the epilogue masks (TSTR=126).
            bf16x8 af[3];
#pragma unroll
            for (int k = 0; k < 3; ++k)
                af[k] = *(const bf16x8*)(Ab + sA[k] + mf * (16 * BK));
#pragma unroll
            for (int nf = 0; nf < 4; ++nf)
#pragma unroll
                for (int k = 0; k < 3; ++k)
                    acc[mf][nf] = __builtin_amdgcn_mfma_f32_16x16x32_bf16(af[k], bfr[k][nf], acc[mf][nf], 0, 0, 0);
        }
    }
#undef STAGE1
    // epilogue: BN+ReLU per cb, store bf16 to Xws[n][t][cb], mask local<126 & t<400
    float sc[4], bo[4];
#pragma unroll
    for (int nf = 0; nf < 4; ++nf) {
        int cb = cb0 + wvN * 64 + nf * 16 + lrow;
        float s0 = bn_g[cb] * rsqrtf(bn_v[cb] + 1e-5f);
        sc[nf] = s0;
        bo[nf] = bn_b[cb] - bn_m[cb] * s0;
    }
#pragma unroll
    for (int mf = 0; mf < 4; ++mf) {
#pragma unroll
        for (int r = 0; r < 4; ++r) {
            int local = wvM * 64 + mf * 16 + quad * 4 + r;
            int t = tm + local;
            if (local < TSTR && t < LT_) {
#pragma unroll
                for (int nf = 0; nf < 4; ++nf) {
                    int cb = cb0 + wvN * 64 + nf * 16 + lrow;
                    float v = fmaxf(fmaf(acc[mf][nf][r], sc[nf], bo[nf]), 0.f);
                    Xws[((size_t)n * LT_ + t) * CB_ + cb] = f2bf(v);
                }
            }
        }
    }
}

// ---------------- G2: gate[n][c][t] = sigmoid(W2 @ X), bf16 out
// same double-buffered gload_lds + swizzle structure; M=c, N=t, K=cb.
__global__ __launch_bounds__(256, 3) void k_gemm2(
    const ushort_t* __restrict__ Xws, const ushort_t* __restrict__ w2b,
    ushort_t* __restrict__ gate) {
    __shared__ __align__(16) ushort_t Asm[2 * 128 * BK];   // 16 KB
    __shared__ __align__(16) ushort_t Bsm[2 * 128 * BK];   // 16 KB
    const int tid = threadIdx.x;
    const int n  = blockIdx.z;
    const int cm = blockIdx.x * 128;
    const int tt = blockIdx.y * 128;
    const int lane = tid & 63, lrow = lane & 15, quad = lane >> 4;
    const int wv = tid >> 6, wvM = wv & 1, wvN = wv >> 1;

    const int srow = lane >> 2;
    const int csrc = (((lane & 3) ^ ((lane >> 3) & 3)) << 3);
    const ushort_t* gA[2];
    const ushort_t* gB[2];
#pragma unroll
    for (int i = 0; i < 2; ++i) {
        int r = (2 * wv + i) * 16 + srow;
        gA[i] = w2b + (size_t)(cm + r) * CB_ + csrc;
        int tr = tt + r; tr = tr < LT_ - 1 ? tr : LT_ - 1;  // clamp; outputs masked
        gB[i] = Xws + ((size_t)n * LT_ + tr) * CB_ + csrc;
    }
    const int sOff = lrow * BK + ((quad ^ ((lrow >> 1) & 3)) << 3);

    f32x4 acc[4][4];
#pragma unroll
    for (int i = 0; i < 4; ++i)
#pragma unroll
        for (int j = 0; j < 4; ++j) acc[i][j] = (f32x4){0.f, 0.f, 0.f, 0.f};

#define STAGE2(buf)                                                         \
    {                                                                       \
        ushort_t* ad = Asm + (buf) * (128 * BK) + (2 * wv) * (16 * BK);     \
        ushort_t* bd = Bsm + (buf) * (128 * BK) + (2 * wv) * (16 * BK);     \
        gload16(gA[0], ad);                                                 \
        gload16(gA[1], ad + 16 * BK);                                       \
        gload16(gB[0], bd);                                                 \
        gload16(gB[1], bd + 16 * BK);                                       \
        gA[0] += BK; gA[1] += BK; gB[0] += BK; gB[1] += BK;                 \
    }

    STAGE2(0);
    for (int s = 0; s < CB_ / BK; ++s) {
        __syncthreads();
        const int cur = s & 1;
        if (s + 1 < CB_ / BK) STAGE2(cur ^ 1);
        const ushort_t* Ab = Asm + cur * (128 * BK) + wvM * (64 * BK) + sOff;
        const ushort_t* Bb = Bsm + cur * (128 * BK) + wvN * (64 * BK) + sOff;
        bf16x8 af[4], bfm[4];
#pragma unroll
        for (int mf = 0; mf < 4; ++mf)
            af[mf] = *(const bf16x8*)(Ab + mf * (16 * BK));
#pragma unroll
        for (int nf = 0; nf < 4; ++nf)
            bfm[nf] = *(const bf16x8*)(Bb + nf * (16 * BK));
#pragma unroll
        for (int mf = 0; mf < 4; ++mf)
#pragma unroll
            for (int nf = 0; nf < 4; ++nf)
                acc[mf][nf] = __builtin_amdgcn_mfma_f32_16x16x32_bf16(af[mf], bfm[nf], acc[mf][nf], 0, 0, 0);
    }
#undef STAGE2
#pragma unroll
    for (int mf = 0; mf < 4; ++mf) {
#pragma unroll
        for (int r = 0; r < 4; ++r) {
            int c = cm + wvM * 64 + mf * 16 + quad * 4 + r;
#pragma unroll
            for (int nf = 0; nf < 4; ++nf) {
                int t = tt + wvN * 64 + nf * 16 + lrow;
                if (t < LT_) {
                    float g = 1.f / (1.f + __expf(-acc[mf][nf][r]));
                    gate[((size_t)n * C_ + c) * LT_ + t] = f2bf(g);
                }
            }
        }
    }
}

// ---------------- G3: out[n][c][t] = sum_i kern[n][c][i] * (lt*gate)[t+i-1]
__global__ __launch_bounds__(256) void k_final(
    const float* __restrict__ lt, const ushort_t* __restrict__ gate,
    const float* __restrict__ kern, float* __restrict__ out) {
    long long idx = (long long)blockIdx.x * 256 + threadIdx.x;  // over N*C*100
    int t0 = (int)(idx % 100) * 4;
    long long nc = idx / 100;
    const float*   ltp = lt   + (size_t)nc * LT_;
    const ushort_t* gp = gate + (size_t)nc * LT_;
    float4 kv = *(const float4*)(kern + (size_t)nc * 4);
    float nl[6];
#pragma unroll
    for (int j = -1; j <= 4; ++j) {
        int t = t0 + j;
        nl[j + 1] = (t >= 0 && t < LT_) ? ltp[t] * bf2f(gp[t]) : 0.f;
    }
    float4 o;
    o.x = kv.x * nl[0] + kv.y * nl[1] + kv.z * nl[2];
    o.y = kv.x * nl[1] + kv.y * nl[2] + kv.z * nl[3];
    o.z = kv.x * nl[2] + kv.y * nl[3] + kv.z * nl[4];
    o.w = kv.x * nl[3] + kv.y * nl[4] + kv.z * nl[5];
    *(float4*)(out + (size_t)nc * LT_ + t0) = o;
}

extern "C" void kernel_launch(void* const* d_in, const int* in_sizes, int n_in,
                              void* d_out, int out_size, void* d_ws, size_t ws_size,
                              hipStream_t stream) {
    const float* st   = (const float*)d_in[0];
    const float* lt   = (const float*)d_in[1];
    const float* g_w1 = (const float*)d_in[2];
    const float* g_bg = (const float*)d_in[3];
    const float* g_bb = (const float*)d_in[4];
    const float* g_bm = (const float*)d_in[5];
    const float* g_bv = (const float*)d_in[6];
    const float* g_w2 = (const float*)d_in[7];
    const float* l_w1 = (const float*)d_in[8];
    const float* l_bg = (const float*)d_in[9];
    const float* l_bb = (const float*)d_in[10];
    const float* l_bm = (const float*)d_in[11];
    const float* l_bv = (const float*)d_in[12];
    const float* l_w2 = (const float*)d_in[13];
    float* out = (float*)d_out;

    char* ws = (char*)d_ws;
    // workspace layout (bytes)
    float*    kern = (float*)(ws + 0);                    // 1,048,576
    ushort_t* w1b  = (ushort_t*)(ws + 1048576);           // 6,291,456
    ushort_t* w2b  = (ushort_t*)(ws + 7340032);           // 2,097,152
    ushort_t* Xws  = (ushort_t*)(ws + 9437184);           // 13,107,200
    ushort_t* ltT  = (ushort_t*)(ws + 22544384);          // 52,690,944
    ushort_t* gate = ltT;                                 // alias: ltT dead after G1

    k_global<<<dim3((N_ * C_) / 256), dim3(256), 0, stream>>>(
        st, g_w1, g_bg, g_bb, g_bm, g_bv, g_w2, kern);
    k_w1<<<dim3((CB_ * C_) / 256), dim3(256), 0, stream>>>(l_w1, w1b);
    k_w2<<<dim3((C_ * CB_) / 256), dim3(256), 0, stream>>>(l_w2, w2b);
    k_zero<<<dim3((N_ * C_) / 256), dim3(256), 0, stream>>>(ltT);
    k_transpose<<<dim3(13, C_ / 32, N_), dim3(256), 0, stream>>>(lt, ltT);
    k_gemm1<<<dim3(4, 4, N_), dim3(256), 0, stream>>>(
        ltT, w1b, l_bg, l_bb, l_bm, l_bv, Xws);
    k_gemm2<<<dim3(C_ / 128, 4, N_), dim3(256), 0, stream>>>(Xws, w2b, gate);
    k_final<<<dim3((N_ * C_ * (LT_ / 4)) / 256), dim3(256), 0, stream>>>(
        lt, gate, kern, out);
}